// Round 1
// baseline (532.930 us; speedup 1.0000x reference)
//
#include <hip/hip_runtime.h>

typedef __attribute__((ext_vector_type(8))) short short8;
typedef __attribute__((ext_vector_type(4))) float f32x4;

#define SEQ 2048
#define BATCH 64
#define HID 512
#define ATT 512

__device__ __forceinline__ unsigned short f2bf(float f) {
  unsigned u = __float_as_uint(f);
  u += 0x7fffu + ((u >> 16) & 1u);   // round-to-nearest-even
  return (unsigned short)(u >> 16);
}

// Pre-kernel: blocks 0..63 compute dec_att rows (fp32); blocks 64..127 convert W_s -> bf16.
__global__ void bahdanau_pre(const float* __restrict__ dec_out,
                             const float* __restrict__ W_t,
                             const float* __restrict__ b_t,
                             const float* __restrict__ W_s,
                             unsigned short* __restrict__ wsb,
                             float* __restrict__ dec_att) {
  if (blockIdx.x < 64) {
    const int b = blockIdx.x;
    __shared__ float drow[HID];
    for (int i = threadIdx.x; i < HID; i += 256) drow[i] = dec_out[b * HID + i];
    __syncthreads();
    for (int a = threadIdx.x; a < ATT; a += 256) {
      const float4* wr = (const float4*)(W_t + (size_t)a * HID);
      float s0 = 0.f, s1 = 0.f, s2 = 0.f, s3 = 0.f;
#pragma unroll 4
      for (int j = 0; j < HID / 4; ++j) {
        float4 w = wr[j];
        s0 = fmaf(w.x, drow[4 * j + 0], s0);
        s1 = fmaf(w.y, drow[4 * j + 1], s1);
        s2 = fmaf(w.z, drow[4 * j + 2], s2);
        s3 = fmaf(w.w, drow[4 * j + 3], s3);
      }
      dec_att[b * ATT + a] = (s0 + s1) + (s2 + s3) + b_t[a];
    }
  } else {
    const int cb = blockIdx.x - 64;                   // 0..63, 1024 float4 each
    const float4* src = (const float4*)W_s;
#pragma unroll
    for (int i = 0; i < 4; ++i) {
      int idx = cb * 1024 + i * 256 + threadIdx.x;    // < 65536
      float4 v = src[idx];
      ushort4 o;
      o.x = f2bf(v.x); o.y = f2bf(v.y); o.z = f2bf(v.z); o.w = f2bf(v.w);
      ((ushort4*)wsb)[idx] = o;
    }
  }
}

// Main: block = one s (64 rows = all b). 8 waves x (64m x 64n), full K in 16 steps of 32.
// A (enc) fp32 -> bf16 staged through 8KB double-buffered LDS; B (W_s bf16) streamed from L2
// into registers with 1-step prefetch. Fused tanh + v_a reduction epilogue.
__global__ __launch_bounds__(512, 2)
void bahdanau_main(const float* __restrict__ enc,
                   const unsigned short* __restrict__ wsb,
                   const float* __restrict__ dec_att,
                   const float* __restrict__ v_a,
                   float* __restrict__ out) {
  // LDS layout: Alds[buf][(q*64 + row)*8 + j]  for element (row, k=q*8+j) of the 64x32 chunk.
  // Lane-sequential: a-frag read is 16 consecutive 16B blocks per quad -> 2-way (free) banks.
  __shared__ __align__(16) unsigned short Alds[2][2048];
  __shared__ float partial[8 * 64];

  const int tid  = threadIdx.x;
  const int wave = tid >> 6;
  const int lane = tid & 63;
  const int c = lane & 15;          // MFMA frag row-index / D column
  const int q = lane >> 4;          // quad: k-offset q*8 in frags, D row group
  const int s = blockIdx.x;
  const int n0 = wave * 64;

  // Staging: thread t loads floats [skc..skc+3] of row srow of the current 64x32 chunk.
  const int srow = tid >> 3;                          // 0..63
  const int skc  = (tid & 7) * 4;                     // 0..28
  const int ldst = ((skc >> 3) * 64 + srow) * 8 + (skc & 7);
  const float* gsrc = enc + ((size_t)s * 64 + srow) * HID + skc;

  // b-frag base: lane reads W_s_bf16[n0 + nt*16 + c][kk*32 + q*8 .. +7]
  const unsigned short* bsrc = wsb + (size_t)(n0 + c) * HID + q * 8;

  f32x4 acc[4][4] = {};   // [m-tile][n-tile], 64 fp32/lane

  // stage chunk 0
  {
    float4 v = *(const float4*)gsrc;
    ushort4 o;
    o.x = f2bf(v.x); o.y = f2bf(v.y); o.z = f2bf(v.z); o.w = f2bf(v.w);
    *(ushort4*)&Alds[0][ldst] = o;
  }
  // prefetch b-frags for kk=0
  short8 bp[4];
#pragma unroll
  for (int nt = 0; nt < 4; ++nt)
    bp[nt] = *(const short8*)(bsrc + (size_t)nt * 16 * HID);
  __syncthreads();

#pragma unroll
  for (int kk = 0; kk < 16; ++kk) {
    const int cur = kk & 1;

    short8 bfr[4];
#pragma unroll
    for (int nt = 0; nt < 4; ++nt) bfr[nt] = bp[nt];

    // issue next A chunk global load early (consumed at end of this iteration)
    float4 stg;
    if (kk < 15) stg = *(const float4*)(gsrc + (kk + 1) * 32);

    // prefetch next b-frags (consumed next iteration)
    if (kk < 15) {
#pragma unroll
      for (int nt = 0; nt < 4; ++nt)
        bp[nt] = *(const short8*)(bsrc + (size_t)nt * 16 * HID + (kk + 1) * 32);
    }

    // a-frags from LDS: row = mt*16 + c, k-offset = q*8
    const unsigned short* ab = &Alds[cur][(q * 64 + c) * 8];
    short8 a[4];
#pragma unroll
    for (int mt = 0; mt < 4; ++mt)
      a[mt] = *(const short8*)(ab + mt * 16 * 8);

#pragma unroll
    for (int mt = 0; mt < 4; ++mt)
#pragma unroll
      for (int nt = 0; nt < 4; ++nt)
        acc[mt][nt] = __builtin_amdgcn_mfma_f32_16x16x32_bf16(a[mt], bfr[nt], acc[mt][nt], 0, 0, 0);

    // convert + write next chunk into the other buffer
    if (kk < 15) {
      ushort4 o;
      o.x = f2bf(stg.x); o.y = f2bf(stg.y); o.z = f2bf(stg.z); o.w = f2bf(stg.w);
      *(ushort4*)&Alds[cur ^ 1][ldst] = o;
    }
    __syncthreads();
  }

  // ---- epilogue: x = acc + dec_att[b][n]; t = tanh(x); score += v_a[n]*t ----
  float va[4];
#pragma unroll
  for (int nt = 0; nt < 4; ++nt) va[nt] = v_a[n0 + nt * 16 + c];

  float rowsum[4][4];   // [mt][reg] -> row b = mt*16 + q*4 + r
#pragma unroll
  for (int mt = 0; mt < 4; ++mt) {
#pragma unroll
    for (int r = 0; r < 4; ++r) {
      const int ml = mt * 16 + q * 4 + r;             // = batch index b
      float sum = 0.f;
#pragma unroll
      for (int nt = 0; nt < 4; ++nt) {
        const int n = n0 + nt * 16 + c;
        float x = acc[mt][nt][r] + dec_att[ml * ATT + n];
        // tanh(x) = 1 - 2/(exp2(2*log2e*x)+1); saturates correctly at +-inf
        float e = __builtin_amdgcn_exp2f(x * 2.8853900817779268f);
        float t = 1.f - 2.f * __builtin_amdgcn_rcpf(e + 1.f);
        sum = fmaf(va[nt], t, sum);
      }
      rowsum[mt][r] = sum;
    }
  }

  // reduce across the 16 lanes sharing a row (butterfly within 16-lane groups)
#pragma unroll
  for (int off = 1; off < 16; off <<= 1) {
#pragma unroll
    for (int mt = 0; mt < 4; ++mt)
#pragma unroll
      for (int r = 0; r < 4; ++r)
        rowsum[mt][r] += __shfl_xor(rowsum[mt][r], off, 64);
  }

  if (c == 0) {
#pragma unroll
    for (int mt = 0; mt < 4; ++mt)
#pragma unroll
      for (int r = 0; r < 4; ++r)
        partial[wave * 64 + mt * 16 + q * 4 + r] = rowsum[mt][r];
  }
  __syncthreads();

  if (tid < 64) {
    float sum = 0.f;
#pragma unroll
    for (int w = 0; w < 8; ++w) sum += partial[w * 64 + tid];
    out[(size_t)tid * SEQ + s] = sum;    // out[b][s]
  }
}

extern "C" void kernel_launch(void* const* d_in, const int* in_sizes, int n_in,
                              void* d_out, int out_size, void* d_ws, size_t ws_size,
                              hipStream_t stream) {
  const float* dec_out = (const float*)d_in[0];   // (64, 512)
  const float* enc     = (const float*)d_in[1];   // (2048, 64, 512)
  const float* W_s     = (const float*)d_in[2];   // (512, 512)
  const float* W_t     = (const float*)d_in[3];   // (512, 512)
  const float* b_t     = (const float*)d_in[4];   // (512,)
  const float* v_a     = (const float*)d_in[5];   // (512,)
  float* out = (float*)d_out;                     // (64, 2048)

  unsigned short* wsb = (unsigned short*)d_ws;                      // 512 KB: W_s bf16
  float* dec_att = (float*)((char*)d_ws + (size_t)ATT * HID * 2);   // 128 KB: dec_att fp32

  bahdanau_pre<<<128, 256, 0, stream>>>(dec_out, W_t, b_t, W_s, wsb, dec_att);
  bahdanau_main<<<SEQ, 512, 0, stream>>>(enc, wsb, dec_att, v_a, out);
}